// Round 6
// baseline (290659.277 us; speedup 1.0000x reference)
//
#include <hip/hip_runtime.h>
#include <hip/hip_bf16.h>
#include <stdint.h>

typedef __hip_bfloat16 bf16;
typedef __attribute__((ext_vector_type(8))) short short8;
typedef __attribute__((ext_vector_type(4))) float f32x4;
typedef __attribute__((ext_vector_type(4))) unsigned int u32x4;

#define NB   64
#define NT   2048
#define NV   32000
#define ND   256
#define NH4  1024
#define NCLS 27
#define POIS 0x7F807F80u

// ---------------- dtype conversion / packing ----------------

__global__ __launch_bounds__(256) void k_cvt_embed(const float* __restrict__ e,
                                                   bf16* __restrict__ o) {
  int i = blockIdx.x * blockDim.x + threadIdx.x;
  float4 v = reinterpret_cast<const float4*>(e)[i];
  union { bf16 h[4]; uint2 u; } pk;
  pk.h[0] = __float2bfloat16(v.x);
  pk.h[1] = __float2bfloat16(v.y);
  pk.h[2] = __float2bfloat16(v.z);
  pk.h[3] = __float2bfloat16(v.w);
  reinterpret_cast<uint2*>(o)[i] = pk.u;
}

// Wi [256][1024] f32 -> Wi_t [1024][256] bf16
__global__ __launch_bounds__(256) void k_cvt_wi(const float* __restrict__ wi,
                                                bf16* __restrict__ wit) {
  int i = blockIdx.x * blockDim.x + threadIdx.x;
  int col = i >> 8;
  int k   = i & 255;
  wit[i] = __float2bfloat16(wi[k * NH4 + col]);
}

// Wh [256][1024] f32 -> packed MFMA B-fragments
__global__ __launch_bounds__(256) void k_cvt_whp(const float* __restrict__ wh,
                                                 bf16* __restrict__ whp) {
  int idx  = blockIdx.x * blockDim.x + threadIdx.x;
  int i    = idx & 7;
  int lane = (idx >> 3) & 63;
  int kg   = (idx >> 9) & 7;
  int nt   = idx >> 12;
  int k = kg * 32 + (lane >> 4) * 8 + i;
  int n = nt * 16 + (lane & 15);
  whp[idx] = __float2bfloat16(wh[k * NH4 + n]);
}

// poison h slots 1..tn (each chunk, before k_lstm) -> replay-deterministic
__global__ __launch_bounds__(256) void k_poison(unsigned* __restrict__ hb, int ndw) {
  int i = blockIdx.x * blockDim.x + threadIdx.x;
  if (i < ndw) hb[8192 + i] = POIS;   // slot 0 skipped (comes from hst)
}

// ---------------- zx = embed[tokens] @ Wi, written PERMUTED ----------------
// zxp byte addr for (b, lt, col): lt*131072 + g*8192 + w*2048 + rq*512 + i*128
//   + u*8 + q*2   where col=q*256+g*16+u, b=w*16+rq*4+i. Scan thread (g,w,rq,u)
// then reads 4 x 8B contiguous per step.
__global__ __launch_bounds__(256) void k_gemm_zx(const int*  __restrict__ tokens,
                                                 const bf16* __restrict__ eb,
                                                 const bf16* __restrict__ wit,
                                                 char* __restrict__ zxp,
                                                 int t0, int lgch) {
  __shared__ bf16 As[4 * 64 * 8];
  __shared__ bf16 Bs[4 * 64 * 8];
  int bid  = blockIdx.x;
  int nb   = bid & 15;
  int mb   = bid >> 4;
  int m0   = mb * 64, n0 = nb * 64;
  int tid  = threadIdx.x, lane = tid & 63, wave = tid >> 6;
  int wm   = wave >> 1, wn = wave & 1;
  int srow = tid >> 2;
  int skg  = tid & 3;

  int r    = m0 + srow;
  int bidx = r >> lgch;
  int lt   = r & ((1 << lgch) - 1);
  long trow = (long)tokens[bidx * NT + t0 + lt] * ND;
  const bf16* ap = eb  + trow + skg * 8;
  const bf16* bp = wit + (long)(n0 + srow) * ND + skg * 8;
  bf16* as_dst = &As[(skg * 64 + srow) * 8];
  bf16* bs_dst = &Bs[(skg * 64 + srow) * 8];

  f32x4 acc[2][2] = {};
  for (int k0 = 0; k0 < ND; k0 += 32) {
    __syncthreads();
    *(u32x4*)as_dst = *(const u32x4*)(ap + k0);
    *(u32x4*)bs_dst = *(const u32x4*)(bp + k0);
    __syncthreads();
    short8 a0 = *(const short8*)&As[((lane >> 4) * 64 + wm * 32 +  0 + (lane & 15)) * 8];
    short8 a1 = *(const short8*)&As[((lane >> 4) * 64 + wm * 32 + 16 + (lane & 15)) * 8];
    short8 b0 = *(const short8*)&Bs[((lane >> 4) * 64 + wn * 32 +  0 + (lane & 15)) * 8];
    short8 b1 = *(const short8*)&Bs[((lane >> 4) * 64 + wn * 32 + 16 + (lane & 15)) * 8];
    acc[0][0] = __builtin_amdgcn_mfma_f32_16x16x32_bf16(a0, b0, acc[0][0], 0, 0, 0);
    acc[0][1] = __builtin_amdgcn_mfma_f32_16x16x32_bf16(a0, b1, acc[0][1], 0, 0, 0);
    acc[1][0] = __builtin_amdgcn_mfma_f32_16x16x32_bf16(a1, b0, acc[1][0], 0, 0, 0);
    acc[1][1] = __builtin_amdgcn_mfma_f32_16x16x32_bf16(a1, b1, acc[1][1], 0, 0, 0);
  }
  int r_base = m0 + wm * 32 + (lane >> 4) * 4;
  int c_base = n0 + wn * 32 + (lane & 15);
  int mask = (1 << lgch) - 1;
#pragma unroll
  for (int fm = 0; fm < 2; ++fm)
#pragma unroll
    for (int fn = 0; fn < 2; ++fn)
#pragma unroll
      for (int i2 = 0; i2 < 4; ++i2) {
        int rr  = r_base + fm * 16 + i2;
        int col = c_base + fn * 16;
        int b   = rr >> lgch, lt2 = rr & mask;
        int q   = col >> 8, gg = (col >> 4) & 15, uu = col & 15;
        int w_  = b >> 4, rq_ = (b >> 2) & 3, ii = b & 3;
        size_t off = (size_t)lt2 * 131072 + gg * 8192 + w_ * 2048 + rq_ * 512 +
                     ii * 128 + uu * 8 + q * 2;
        *(bf16*)(zxp + off) = __float2bfloat16(acc[fm][fn][i2]);
      }
}

// ---------------- LSTM scan, pairwise exchange ----------------
// 8 WGs x 512 threads (8 waves, 1 WG/CU). WG (p = wid>>1, s = wid&1) owns
// batches [16p,16p+16) x units [128s,128s+128). Wave wv -> unit group
// G = s*8+wv (16 units). Full Wh k-range register-resident per wave
// (bw[4][8] = 128 VGPR). Per step: own h-half exchanged intra-WG via LDS
// (parity double-buffer, 1 barrier); partner h-half exchanged via global
// slot in MFMA-A-fragment-major layout (coalesced 1KB/instr), relaxed agent
// atomics polled against bf16-inf poison. Schedule: publish early, own-half
// MFMAs while partner's store propagates, then poll + partner MFMAs.
__device__ __forceinline__ float sigf(float x) {
  return __builtin_amdgcn_rcpf(1.f + __expf(-x));
}
__device__ __forceinline__ float tanh_fast(float x) {
  return 1.f - 2.f * __builtin_amdgcn_rcpf(1.f + __expf(2.f * x));
}
__device__ __forceinline__ unsigned short f2b(float x) {
  bf16 t = __float2bfloat16(x);
  return *reinterpret_cast<unsigned short*>(&t);
}

union Frag { unsigned long long q[2]; short8 s; };

__global__ __launch_bounds__(512, 1) void k_lstm(const char* __restrict__ zxp,
                                                 const bf16* __restrict__ whp,
                                                 const float* __restrict__ bh,
                                                 float* __restrict__ cst,
                                                 float* __restrict__ hst,
                                                 unsigned* __restrict__ hbuf,
                                                 int t0, int tn) {
  __shared__ unsigned hs[2][1024];   // [parity][own-half 4KB in fragment layout]

  int wid = blockIdx.x;
  int p   = wid >> 1;          // batch tile: batches [16p, 16p+16)
  int s   = wid & 1;           // unit half: units [128s, 128s+128)
  int tid = threadIdx.x;
  int l   = tid & 63;
  int wv  = tid >> 6;          // wave 0..7
  int G   = s * 8 + wv;        // unit group 0..15
  int l15 = l & 15, l4 = l >> 4;
  int u   = G * 16 + l15;      // this lane's unit

  // register-resident Wh B-fragments (all 8 k-tiles, 4 gate n-tiles)
  short8 bw[4][8];
#pragma unroll
  for (int q = 0; q < 4; ++q) {
    int nt = q * 16 + G;
#pragma unroll
    for (int k0 = 0; k0 < 8; ++k0)
      bw[q][k0] = *(const short8*)&whp[((long)(nt * 8 + k0) * 64 + l) * 8];
  }
  float bhv[4];
#pragma unroll
  for (int q = 0; q < 4; ++q) bhv[q] = bh[q * 256 + u];

  float c[4];
#pragma unroll
  for (int i = 0; i < 4; ++i)
    c[i] = (t0 == 0) ? 0.f : cst[(p * 16 + l4 * 4 + i) * 256 + u];

  // initial A-fragments of h(t0), both halves: zeros or hst
  short8 a[8];
  if (t0 == 0) {
#pragma unroll
    for (int k0 = 0; k0 < 8; ++k0) a[k0] = (short8)(short)0;
  } else {
    int rowb = p * 16 + l15;
#pragma unroll
    for (int k0 = 0; k0 < 8; ++k0) {
      const float* hp = &hst[rowb * 256 + l4 * 8 + k0 * 32];
      float4 f0 = *(const float4*)hp;
      float4 f1 = *(const float4*)(hp + 4);
      unsigned short e[8] = {f2b(f0.x), f2b(f0.y), f2b(f0.z), f2b(f0.w),
                             f2b(f1.x), f2b(f1.y), f2b(f1.z), f2b(f1.w)};
      a[k0] = *(const short8*)e;
    }
  }

  const char* zbase = zxp + G * 8192 + p * 2048 + l4 * 512 + l15 * 8;
  unsigned long long* hb64 = (unsigned long long*)hbuf;

  // zx prefetch for step 0
  uint2 z0[4], z1[4];
#pragma unroll
  for (int i = 0; i < 4; ++i) z0[i] = *(const uint2*)(zbase + i * 128);

  // producer/consumer constants
  int hi    = (2 * G + (l15 >> 3)) & 3;   // dest-lane hi bits of this lane's unit
  int rown  = (G >> 1) & 3;               // own k0rel (region r) for publishing
  int jw    = (l15 & 7) >> 1;             // dword-within-16B
  int k0own = 4 * s, k0par = 4 * (1 - s);

  for (int lt = 0; lt < tn; ++lt) {
    // prefetch next step's zx (independent of h)
    if (lt + 1 < tn) {
#pragma unroll
      for (int i = 0; i < 4; ++i)
        z1[i] = *(const uint2*)(zbase + (size_t)(lt + 1) * 131072 + i * 128);
    }

    // own half A-fragments from LDS (written last iter, parity lt&1)
    if (lt > 0) {
      const unsigned* hp = hs[lt & 1];
#pragma unroll
      for (int r = 0; r < 4; ++r)
        a[k0own + r] = *(const short8*)&hp[(r * 64 + l) * 4];
    }

    // own-half MFMAs first (hides partner store->visibility latency)
    f32x4 acc[4] = {};
#pragma unroll
    for (int r = 0; r < 4; ++r) {
#pragma unroll
      for (int q = 0; q < 4; ++q)
        acc[q] = __builtin_amdgcn_mfma_f32_16x16x32_bf16(a[k0own + r], bw[q][k0own + r],
                                                         acc[q], 0, 0, 0);
    }

    // partner half: poll its 4KB fragment region (coalesced), bounded spin
    if (lt > 0) {
      unsigned long long* sb = hb64 + (size_t)lt * 4096 + p * 1024 + (1 - s) * 512;
      Frag fr[4];
      for (unsigned spin = 0; spin < 65536u; ++spin) {
#pragma unroll
        for (int r = 0; r < 4; ++r) {
          fr[r].q[0] = __hip_atomic_load(sb + (r * 64 + l) * 2,
                                         __ATOMIC_RELAXED, __HIP_MEMORY_SCOPE_AGENT);
          fr[r].q[1] = __hip_atomic_load(sb + (r * 64 + l) * 2 + 1,
                                         __ATOMIC_RELAXED, __HIP_MEMORY_SCOPE_AGENT);
        }
        bool bad = false;
#pragma unroll
        for (int r = 0; r < 4; ++r) {
          unsigned long long q0 = fr[r].q[0], q1 = fr[r].q[1];
          bad |= ((unsigned)q0 == POIS) | ((unsigned)(q0 >> 32) == POIS) |
                 ((unsigned)q1 == POIS) | ((unsigned)(q1 >> 32) == POIS);
        }
        if (!__any(bad)) break;
      }
#pragma unroll
      for (int r = 0; r < 4; ++r) a[k0par + r] = fr[r].s;
    }

#pragma unroll
    for (int r = 0; r < 4; ++r) {
#pragma unroll
      for (int q = 0; q < 4; ++q)
        acc[q] = __builtin_amdgcn_mfma_f32_16x16x32_bf16(a[k0par + r], bw[q][k0par + r],
                                                         acc[q], 0, 0, 0);
    }

    // gates: lane owns (4 batches x unit u)
    unsigned my[4];
    float hv[4];
#pragma unroll
    for (int i = 0; i < 4; ++i) {
      float zi = acc[0][i] + __uint_as_float((z0[i].x & 0xFFFFu) << 16) + bhv[0];
      float zf = acc[1][i] + __uint_as_float((z0[i].x >> 16) << 16)     + bhv[1];
      float zg = acc[2][i] + __uint_as_float((z0[i].y & 0xFFFFu) << 16) + bhv[2];
      float zo = acc[3][i] + __uint_as_float((z0[i].y >> 16) << 16)     + bhv[3];
      c[i] = sigf(zf) * c[i] + sigf(zi) * tanh_fast(zg);
      hv[i] = sigf(zo) * tanh_fast(c[i]);
      my[i] = f2b(hv[i]);
    }

    // pack unit-pairs cross-lane; publish to partner (global, fragment-major)
    // and to own LDS parity buffer. dword idx = (rown*64 + dl)*4 + jw,
    // dl = (batch offset) | (hi<<4).
    unsigned pt[4];
#pragma unroll
    for (int i = 0; i < 4; ++i) pt[i] = (unsigned)__shfl_xor((int)my[i], 1, 64);
    bool even = ((l & 1) == 0);
    int i0 = even ? 0 : 2;
    unsigned* gdst = hbuf + (size_t)(lt + 1) * 8192 + p * 2048 + s * 1024;
    unsigned* ldst = hs[(lt + 1) & 1];
#pragma unroll
    for (int k = 0; k < 2; ++k) {
      int i = i0 + k;
      unsigned dw = even ? (my[i] | (pt[i] << 16)) : (pt[i] | (my[i] << 16));
      int idx = (rown * 64 + ((l4 * 4 + i) | (hi << 4))) * 4 + jw;
      __hip_atomic_store(gdst + idx, dw, __ATOMIC_RELAXED, __HIP_MEMORY_SCOPE_AGENT);
      ldst[idx] = dw;
    }

    if (lt == tn - 1) {
#pragma unroll
      for (int i = 0; i < 4; ++i)
        hst[(p * 16 + l4 * 4 + i) * 256 + u] = hv[i];
    }

    __syncthreads();
#pragma unroll
    for (int i = 0; i < 4; ++i) z0[i] = z1[i];
  }

#pragma unroll
  for (int i = 0; i < 4; ++i)
    cst[(p * 16 + l4 * 4 + i) * 256 + u] = c[i];
}

// ---------------- y = h @ Wo + bo ----------------
__global__ __launch_bounds__(64) void k_out(const float* __restrict__ hfin,
                                            const float* __restrict__ wo,
                                            const float* __restrict__ bo,
                                            float* __restrict__ y) {
  __shared__ float hsm[256];
  int b = blockIdx.x, tid = threadIdx.x;
  for (int i = tid; i < 256; i += 64) hsm[i] = hfin[b * 256 + i];
  __syncthreads();
  if (tid < NCLS) {
    float s = bo[tid];
    for (int k = 0; k < 256; ++k) s += hsm[k] * wo[k * NCLS + tid];
    y[b * NCLS + tid] = s;
  }
}

// ---------------- launcher ----------------
extern "C" void kernel_launch(void* const* d_in, const int* in_sizes, int n_in,
                              void* d_out, int out_size, void* d_ws, size_t ws_size,
                              hipStream_t stream) {
  const int*   tokens = (const int*)d_in[0];
  const float* embed  = (const float*)d_in[3];
  const float* wi     = (const float*)d_in[4];
  const float* wh     = (const float*)d_in[5];
  const float* bh     = (const float*)d_in[6];
  const float* wo     = (const float*)d_in[7];
  const float* bo     = (const float*)d_in[8];
  float* y = (float*)d_out;

  char* ws = (char*)d_ws;
  bf16* eb     = (bf16*)ws;     ws += (size_t)NV * ND * 2;        // 16.38 MB
  bf16* wit    = (bf16*)ws;     ws += (size_t)NH4 * ND * 2;       // 0.5 MB
  bf16* whp    = (bf16*)ws;     ws += (size_t)ND * NH4 * 2;       // 0.5 MB
  float* cst   = (float*)ws;    ws += (size_t)NB * ND * 4;        // 64 KB
  float* hst   = (float*)ws;    ws += (size_t)NB * ND * 4;        // 64 KB
  size_t fixed = (size_t)(ws - (char*)d_ws);

  // pick largest chunk: need = fixed + hbuf((ch+1)*32KB) + zxp(ch*128KB)
  int CHUNK = 32, lgch = 5;
  static const int cand[]  = {2048, 1024, 512, 256, 128, 64, 32};
  static const int candl[] = {11, 10, 9, 8, 7, 6, 5};
  for (int ci = 0; ci < 7; ++ci) {
    size_t need = fixed + (size_t)(cand[ci] + 1) * 32768 + (size_t)cand[ci] * 131072;
    if (need <= ws_size) { CHUNK = cand[ci]; lgch = candl[ci]; break; }
  }
  unsigned* hbuf = (unsigned*)ws;  ws += (size_t)(CHUNK + 1) * 32768;
  char* zxp = ws;

  hipLaunchKernelGGL(k_cvt_embed, dim3(NV * ND / 4 / 256), dim3(256), 0, stream, embed, eb);
  hipLaunchKernelGGL(k_cvt_wi,    dim3(NH4 * ND / 256), dim3(256), 0, stream, wi, wit);
  hipLaunchKernelGGL(k_cvt_whp,   dim3(ND * NH4 / 256), dim3(256), 0, stream, wh, whp);

  for (int t0 = 0; t0 < NT; t0 += CHUNK) {
    hipLaunchKernelGGL(k_gemm_zx, dim3(CHUNK * 16), dim3(256), 0, stream,
                       tokens, eb, wit, zxp, t0, lgch);
    hipLaunchKernelGGL(k_poison, dim3(CHUNK * 32), dim3(256), 0, stream,
                       hbuf, CHUNK * 8192);
    hipLaunchKernelGGL(k_lstm, dim3(8), dim3(512), 0, stream,
                       zxp, whp, bh, cst, hst, hbuf, t0, CHUNK);
  }
  hipLaunchKernelGGL(k_out, dim3(NB), dim3(64), 0, stream, hst, wo, bo, y);
}

// Round 7
// 4211.123 us; speedup vs baseline: 69.0218x; 69.0218x over previous
//
#include <hip/hip_runtime.h>
#include <hip/hip_bf16.h>
#include <stdint.h>

typedef __hip_bfloat16 bf16;
typedef __attribute__((ext_vector_type(8))) short short8;
typedef __attribute__((ext_vector_type(4))) float f32x4;
typedef __attribute__((ext_vector_type(4))) unsigned int u32x4;

#define NB   64
#define NT   2048
#define NV   32000
#define ND   256
#define NH4  1024
#define NCLS 27
#define POIS 0x7F807F80u

// ---------------- dtype conversion / packing ----------------

__global__ __launch_bounds__(256) void k_cvt_embed(const float* __restrict__ e,
                                                   bf16* __restrict__ o) {
  int i = blockIdx.x * blockDim.x + threadIdx.x;
  float4 v = reinterpret_cast<const float4*>(e)[i];
  union { bf16 h[4]; uint2 u; } pk;
  pk.h[0] = __float2bfloat16(v.x);
  pk.h[1] = __float2bfloat16(v.y);
  pk.h[2] = __float2bfloat16(v.z);
  pk.h[3] = __float2bfloat16(v.w);
  reinterpret_cast<uint2*>(o)[i] = pk.u;
}

// Wi [256][1024] f32 -> Wi_t [1024][256] bf16
__global__ __launch_bounds__(256) void k_cvt_wi(const float* __restrict__ wi,
                                                bf16* __restrict__ wit) {
  int i = blockIdx.x * blockDim.x + threadIdx.x;
  int col = i >> 8;
  int k   = i & 255;
  wit[i] = __float2bfloat16(wi[k * NH4 + col]);
}

// Wh [256][1024] f32 -> packed MFMA B-fragments
__global__ __launch_bounds__(256) void k_cvt_whp(const float* __restrict__ wh,
                                                 bf16* __restrict__ whp) {
  int idx  = blockIdx.x * blockDim.x + threadIdx.x;
  int i    = idx & 7;
  int lane = (idx >> 3) & 63;
  int kg   = (idx >> 9) & 7;
  int nt   = idx >> 12;
  int k = kg * 32 + (lane >> 4) * 8 + i;
  int n = nt * 16 + (lane & 15);
  whp[idx] = __float2bfloat16(wh[k * NH4 + n]);
}

// poison h slots 1..tn (each chunk, before k_lstm) -> replay-deterministic
__global__ __launch_bounds__(256) void k_poison(unsigned* __restrict__ hb, int ndw) {
  int i = blockIdx.x * blockDim.x + threadIdx.x;
  if (i < ndw) hb[8192 + i] = POIS;   // slot 0 skipped (comes from hst)
}

// ---------------- zx = embed[tokens] @ Wi, written PERMUTED ----------------
// zxp byte addr for (b, lt, col): lt*131072 + g*8192 + w*2048 + rq*512 + i*128
//   + u*8 + q*2   where col=q*256+g*16+u, b=w*16+rq*4+i.
__global__ __launch_bounds__(256) void k_gemm_zx(const int*  __restrict__ tokens,
                                                 const bf16* __restrict__ eb,
                                                 const bf16* __restrict__ wit,
                                                 char* __restrict__ zxp,
                                                 int t0, int lgch) {
  __shared__ bf16 As[4 * 64 * 8];
  __shared__ bf16 Bs[4 * 64 * 8];
  int bid  = blockIdx.x;
  int nb   = bid & 15;
  int mb   = bid >> 4;
  int m0   = mb * 64, n0 = nb * 64;
  int tid  = threadIdx.x, lane = tid & 63, wave = tid >> 6;
  int wm   = wave >> 1, wn = wave & 1;
  int srow = tid >> 2;
  int skg  = tid & 3;

  int r    = m0 + srow;
  int bidx = r >> lgch;
  int lt   = r & ((1 << lgch) - 1);
  long trow = (long)tokens[bidx * NT + t0 + lt] * ND;
  const bf16* ap = eb  + trow + skg * 8;
  const bf16* bp = wit + (long)(n0 + srow) * ND + skg * 8;
  bf16* as_dst = &As[(skg * 64 + srow) * 8];
  bf16* bs_dst = &Bs[(skg * 64 + srow) * 8];

  f32x4 acc[2][2] = {};
  for (int k0 = 0; k0 < ND; k0 += 32) {
    __syncthreads();
    *(u32x4*)as_dst = *(const u32x4*)(ap + k0);
    *(u32x4*)bs_dst = *(const u32x4*)(bp + k0);
    __syncthreads();
    short8 a0 = *(const short8*)&As[((lane >> 4) * 64 + wm * 32 +  0 + (lane & 15)) * 8];
    short8 a1 = *(const short8*)&As[((lane >> 4) * 64 + wm * 32 + 16 + (lane & 15)) * 8];
    short8 b0 = *(const short8*)&Bs[((lane >> 4) * 64 + wn * 32 +  0 + (lane & 15)) * 8];
    short8 b1 = *(const short8*)&Bs[((lane >> 4) * 64 + wn * 32 + 16 + (lane & 15)) * 8];
    acc[0][0] = __builtin_amdgcn_mfma_f32_16x16x32_bf16(a0, b0, acc[0][0], 0, 0, 0);
    acc[0][1] = __builtin_amdgcn_mfma_f32_16x16x32_bf16(a0, b1, acc[0][1], 0, 0, 0);
    acc[1][0] = __builtin_amdgcn_mfma_f32_16x16x32_bf16(a1, b0, acc[1][0], 0, 0, 0);
    acc[1][1] = __builtin_amdgcn_mfma_f32_16x16x32_bf16(a1, b1, acc[1][1], 0, 0, 0);
  }
  int r_base = m0 + wm * 32 + (lane >> 4) * 4;
  int c_base = n0 + wn * 32 + (lane & 15);
  int mask = (1 << lgch) - 1;
#pragma unroll
  for (int fm = 0; fm < 2; ++fm)
#pragma unroll
    for (int fn = 0; fn < 2; ++fn)
#pragma unroll
      for (int i2 = 0; i2 < 4; ++i2) {
        int rr  = r_base + fm * 16 + i2;
        int col = c_base + fn * 16;
        int b   = rr >> lgch, lt2 = rr & mask;
        int q   = col >> 8, gg = (col >> 4) & 15, uu = col & 15;
        int w_  = b >> 4, rq_ = (b >> 2) & 3, ii = b & 3;
        size_t off = (size_t)lt2 * 131072 + gg * 8192 + w_ * 2048 + rq_ * 512 +
                     ii * 128 + uu * 8 + q * 2;
        *(bf16*)(zxp + off) = __float2bfloat16(acc[fm][fn][i2]);
      }
}

// ---------------- LSTM scan, pairwise exchange ----------------
// 8 WGs x 512 threads. WG (p = wid>>1, s = wid&1) owns batches [16p,16p+16)
// x units [128s,128s+128). Own h-half via LDS parity buffer (1 barrier/step);
// partner h-half via global slot in MFMA-A-fragment-major layout, relaxed
// agent atomics polled against bf16-inf poison.
// RULE-20 FIX vs R6: register arrays are split into _own/_par variants with
// ONLY compile-time indices; runtime s appears solely in memory addresses.
// (R6's a[k0own+r] / bw[q][k0own+r] sent 160 VGPRs to scratch -> 70x slower.)
__device__ __forceinline__ float sigf(float x) {
  return __builtin_amdgcn_rcpf(1.f + __expf(-x));
}
__device__ __forceinline__ float tanh_fast(float x) {
  return 1.f - 2.f * __builtin_amdgcn_rcpf(1.f + __expf(2.f * x));
}
__device__ __forceinline__ unsigned short f2b(float x) {
  bf16 t = __float2bfloat16(x);
  return *reinterpret_cast<unsigned short*>(&t);
}

union Frag { unsigned long long q[2]; short8 s; };

__global__ __launch_bounds__(512, 1) void k_lstm(const char* __restrict__ zxp,
                                                 const bf16* __restrict__ whp,
                                                 const float* __restrict__ bh,
                                                 float* __restrict__ cst,
                                                 float* __restrict__ hst,
                                                 unsigned* __restrict__ hbuf,
                                                 int t0, int tn) {
  __shared__ unsigned hs[2][1024];   // [parity][own-half 4KB in fragment layout]

  int wid = blockIdx.x;
  int p   = wid >> 1;          // batch tile: batches [16p, 16p+16)
  int s   = wid & 1;           // unit half: units [128s, 128s+128)
  int tid = threadIdx.x;
  int l   = tid & 63;
  int wv  = tid >> 6;          // wave 0..7
  int G   = s * 8 + wv;        // unit group 0..15
  int l15 = l & 15, l4 = l >> 4;
  int u   = G * 16 + l15;      // this lane's unit

  // register-resident Wh B-fragments, split own/partner k-halves.
  // own k-tiles = [4s, 4s+4), partner = [4(1-s), 4(1-s)+4).
  short8 bw_own[4][4], bw_par[4][4];
#pragma unroll
  for (int q = 0; q < 4; ++q) {
    int nt = q * 16 + G;
#pragma unroll
    for (int r = 0; r < 4; ++r) {
      bw_own[q][r] = *(const short8*)&whp[((long)(nt * 8 + (4 * s + r)) * 64 + l) * 8];
      bw_par[q][r] = *(const short8*)&whp[((long)(nt * 8 + (4 * (1 - s) + r)) * 64 + l) * 8];
    }
  }
  float bhv[4];
#pragma unroll
  for (int q = 0; q < 4; ++q) bhv[q] = bh[q * 256 + u];

  float c[4];
#pragma unroll
  for (int i = 0; i < 4; ++i)
    c[i] = (t0 == 0) ? 0.f : cst[(p * 16 + l4 * 4 + i) * 256 + u];

  // initial A-fragments of h(t0), both halves: zeros or hst
  short8 a_own[4], a_par[4];
  if (t0 == 0) {
#pragma unroll
    for (int r = 0; r < 4; ++r) { a_own[r] = (short8)(short)0; a_par[r] = (short8)(short)0; }
  } else {
    int rowb = p * 16 + l15;
#pragma unroll
    for (int r = 0; r < 4; ++r) {
      {
        const float* hp = &hst[rowb * 256 + l4 * 8 + (4 * s + r) * 32];
        float4 f0 = *(const float4*)hp;
        float4 f1 = *(const float4*)(hp + 4);
        unsigned short e[8] = {f2b(f0.x), f2b(f0.y), f2b(f0.z), f2b(f0.w),
                               f2b(f1.x), f2b(f1.y), f2b(f1.z), f2b(f1.w)};
        a_own[r] = *(const short8*)e;
      }
      {
        const float* hp = &hst[rowb * 256 + l4 * 8 + (4 * (1 - s) + r) * 32];
        float4 f0 = *(const float4*)hp;
        float4 f1 = *(const float4*)(hp + 4);
        unsigned short e[8] = {f2b(f0.x), f2b(f0.y), f2b(f0.z), f2b(f0.w),
                               f2b(f1.x), f2b(f1.y), f2b(f1.z), f2b(f1.w)};
        a_par[r] = *(const short8*)e;
      }
    }
  }

  const char* zbase = zxp + G * 8192 + p * 2048 + l4 * 512 + l15 * 8;
  unsigned long long* hb64 = (unsigned long long*)hbuf;

  // zx prefetch for step 0
  uint2 z0[4], z1[4];
#pragma unroll
  for (int i = 0; i < 4; ++i) z0[i] = *(const uint2*)(zbase + i * 128);

  // producer constants
  int hi   = (2 * G + (l15 >> 3)) & 3;    // dest-lane hi bits of this lane's unit
  int rown = (G >> 1) & 3;                // own-half region for publishing
  int jw   = (l15 & 7) >> 1;              // dword-within-16B

  for (int lt = 0; lt < tn; ++lt) {
    // prefetch next step's zx (independent of h)
    if (lt + 1 < tn) {
#pragma unroll
      for (int i = 0; i < 4; ++i)
        z1[i] = *(const uint2*)(zbase + (size_t)(lt + 1) * 131072 + i * 128);
    }

    // own half A-fragments from LDS (written last iter, parity lt&1)
    if (lt > 0) {
      const unsigned* hp = hs[lt & 1];
#pragma unroll
      for (int r = 0; r < 4; ++r)
        a_own[r] = *(const short8*)&hp[(r * 64 + l) * 4];
    }

    // own-half MFMAs first (hides partner store->visibility latency)
    f32x4 acc[4] = {};
#pragma unroll
    for (int r = 0; r < 4; ++r) {
#pragma unroll
      for (int q = 0; q < 4; ++q)
        acc[q] = __builtin_amdgcn_mfma_f32_16x16x32_bf16(a_own[r], bw_own[q][r],
                                                         acc[q], 0, 0, 0);
    }

    // partner half: poll its 4KB fragment region (coalesced), bounded spin
    if (lt > 0) {
      unsigned long long* sb = hb64 + (size_t)lt * 4096 + p * 1024 + (1 - s) * 512;
      Frag fr[4];
      for (unsigned spin = 0; spin < 65536u; ++spin) {
#pragma unroll
        for (int r = 0; r < 4; ++r) {
          fr[r].q[0] = __hip_atomic_load(sb + (r * 64 + l) * 2,
                                         __ATOMIC_RELAXED, __HIP_MEMORY_SCOPE_AGENT);
          fr[r].q[1] = __hip_atomic_load(sb + (r * 64 + l) * 2 + 1,
                                         __ATOMIC_RELAXED, __HIP_MEMORY_SCOPE_AGENT);
        }
        bool bad = false;
#pragma unroll
        for (int r = 0; r < 4; ++r) {
          unsigned long long q0 = fr[r].q[0], q1 = fr[r].q[1];
          bad |= ((unsigned)q0 == POIS) | ((unsigned)(q0 >> 32) == POIS) |
                 ((unsigned)q1 == POIS) | ((unsigned)(q1 >> 32) == POIS);
        }
        if (!__any(bad)) break;
      }
#pragma unroll
      for (int r = 0; r < 4; ++r) a_par[r] = fr[r].s;
    }

#pragma unroll
    for (int r = 0; r < 4; ++r) {
#pragma unroll
      for (int q = 0; q < 4; ++q)
        acc[q] = __builtin_amdgcn_mfma_f32_16x16x32_bf16(a_par[r], bw_par[q][r],
                                                         acc[q], 0, 0, 0);
    }

    // gates: lane owns (4 batches x unit u)
    unsigned my[4];
    float hv[4];
#pragma unroll
    for (int i = 0; i < 4; ++i) {
      float zi = acc[0][i] + __uint_as_float((z0[i].x & 0xFFFFu) << 16) + bhv[0];
      float zf = acc[1][i] + __uint_as_float((z0[i].x >> 16) << 16)     + bhv[1];
      float zg = acc[2][i] + __uint_as_float((z0[i].y & 0xFFFFu) << 16) + bhv[2];
      float zo = acc[3][i] + __uint_as_float((z0[i].y >> 16) << 16)     + bhv[3];
      c[i] = sigf(zf) * c[i] + sigf(zi) * tanh_fast(zg);
      hv[i] = sigf(zo) * tanh_fast(c[i]);
      my[i] = f2b(hv[i]);
    }

    // pack unit-pairs cross-lane; publish to partner (global, fragment-major)
    // and to own LDS parity buffer.
    unsigned pt[4];
#pragma unroll
    for (int i = 0; i < 4; ++i) pt[i] = (unsigned)__shfl_xor((int)my[i], 1, 64);
    bool even = ((l & 1) == 0);
    int i0 = even ? 0 : 2;
    unsigned* gdst = hbuf + (size_t)(lt + 1) * 8192 + p * 2048 + s * 1024;
    unsigned* ldst = hs[(lt + 1) & 1];
#pragma unroll
    for (int k = 0; k < 2; ++k) {
      int i = i0 + k;
      unsigned dw = even ? (my[i] | (pt[i] << 16)) : (pt[i] | (my[i] << 16));
      int idx = (rown * 64 + ((l4 * 4 + i) | (hi << 4))) * 4 + jw;
      __hip_atomic_store(gdst + idx, dw, __ATOMIC_RELAXED, __HIP_MEMORY_SCOPE_AGENT);
      ldst[idx] = dw;
    }

    if (lt == tn - 1) {
#pragma unroll
      for (int i = 0; i < 4; ++i)
        hst[(p * 16 + l4 * 4 + i) * 256 + u] = hv[i];
    }

    __syncthreads();
#pragma unroll
    for (int i = 0; i < 4; ++i) z0[i] = z1[i];
  }

#pragma unroll
  for (int i = 0; i < 4; ++i)
    cst[(p * 16 + l4 * 4 + i) * 256 + u] = c[i];
}

// ---------------- y = h @ Wo + bo ----------------
__global__ __launch_bounds__(64) void k_out(const float* __restrict__ hfin,
                                            const float* __restrict__ wo,
                                            const float* __restrict__ bo,
                                            float* __restrict__ y) {
  __shared__ float hsm[256];
  int b = blockIdx.x, tid = threadIdx.x;
  for (int i = tid; i < 256; i += 64) hsm[i] = hfin[b * 256 + i];
  __syncthreads();
  if (tid < NCLS) {
    float s = bo[tid];
    for (int k = 0; k < 256; ++k) s += hsm[k] * wo[k * NCLS + tid];
    y[b * NCLS + tid] = s;
  }
}

// ---------------- launcher ----------------
extern "C" void kernel_launch(void* const* d_in, const int* in_sizes, int n_in,
                              void* d_out, int out_size, void* d_ws, size_t ws_size,
                              hipStream_t stream) {
  const int*   tokens = (const int*)d_in[0];
  const float* embed  = (const float*)d_in[3];
  const float* wi     = (const float*)d_in[4];
  const float* wh     = (const float*)d_in[5];
  const float* bh     = (const float*)d_in[6];
  const float* wo     = (const float*)d_in[7];
  const float* bo     = (const float*)d_in[8];
  float* y = (float*)d_out;

  char* ws = (char*)d_ws;
  bf16* eb     = (bf16*)ws;     ws += (size_t)NV * ND * 2;        // 16.38 MB
  bf16* wit    = (bf16*)ws;     ws += (size_t)NH4 * ND * 2;       // 0.5 MB
  bf16* whp    = (bf16*)ws;     ws += (size_t)ND * NH4 * 2;       // 0.5 MB
  float* cst   = (float*)ws;    ws += (size_t)NB * ND * 4;        // 64 KB
  float* hst   = (float*)ws;    ws += (size_t)NB * ND * 4;        // 64 KB
  size_t fixed = (size_t)(ws - (char*)d_ws);

  // pick largest chunk: need = fixed + hbuf((ch+1)*32KB) + zxp(ch*128KB)
  int CHUNK = 32, lgch = 5;
  static const int cand[]  = {2048, 1024, 512, 256, 128, 64, 32};
  static const int candl[] = {11, 10, 9, 8, 7, 6, 5};
  for (int ci = 0; ci < 7; ++ci) {
    size_t need = fixed + (size_t)(cand[ci] + 1) * 32768 + (size_t)cand[ci] * 131072;
    if (need <= ws_size) { CHUNK = cand[ci]; lgch = candl[ci]; break; }
  }
  unsigned* hbuf = (unsigned*)ws;  ws += (size_t)(CHUNK + 1) * 32768;
  char* zxp = ws;

  hipLaunchKernelGGL(k_cvt_embed, dim3(NV * ND / 4 / 256), dim3(256), 0, stream, embed, eb);
  hipLaunchKernelGGL(k_cvt_wi,    dim3(NH4 * ND / 256), dim3(256), 0, stream, wi, wit);
  hipLaunchKernelGGL(k_cvt_whp,   dim3(ND * NH4 / 256), dim3(256), 0, stream, wh, whp);

  for (int t0 = 0; t0 < NT; t0 += CHUNK) {
    hipLaunchKernelGGL(k_gemm_zx, dim3(CHUNK * 16), dim3(256), 0, stream,
                       tokens, eb, wit, zxp, t0, lgch);
    hipLaunchKernelGGL(k_poison, dim3(CHUNK * 32), dim3(256), 0, stream,
                       hbuf, CHUNK * 8192);
    hipLaunchKernelGGL(k_lstm, dim3(8), dim3(512), 0, stream,
                       zxp, whp, bh, cst, hst, hbuf, t0, CHUNK);
  }
  hipLaunchKernelGGL(k_out, dim3(NB), dim3(64), 0, stream, hst, wo, bo, y);
}

// Round 8
// 4064.196 us; speedup vs baseline: 71.5170x; 1.0362x over previous
//
#include <hip/hip_runtime.h>
#include <hip/hip_bf16.h>
#include <stdint.h>

typedef __hip_bfloat16 bf16;
typedef __attribute__((ext_vector_type(8))) short short8;
typedef __attribute__((ext_vector_type(4))) float f32x4;
typedef __attribute__((ext_vector_type(4))) unsigned int u32x4;

#define NB   64
#define NT   2048
#define NV   32000
#define ND   256
#define NH4  1024
#define NCLS 27
#define POIS 0x7F807F80u

// ---------------- dtype conversion / packing ----------------

__global__ __launch_bounds__(256) void k_cvt_embed(const float* __restrict__ e,
                                                   bf16* __restrict__ o) {
  int i = blockIdx.x * blockDim.x + threadIdx.x;
  float4 v = reinterpret_cast<const float4*>(e)[i];
  union { bf16 h[4]; uint2 u; } pk;
  pk.h[0] = __float2bfloat16(v.x);
  pk.h[1] = __float2bfloat16(v.y);
  pk.h[2] = __float2bfloat16(v.z);
  pk.h[3] = __float2bfloat16(v.w);
  reinterpret_cast<uint2*>(o)[i] = pk.u;
}

// Wi [256][1024] f32 -> Wi_t [1024][256] bf16
__global__ __launch_bounds__(256) void k_cvt_wi(const float* __restrict__ wi,
                                                bf16* __restrict__ wit) {
  int i = blockIdx.x * blockDim.x + threadIdx.x;
  int col = i >> 8;
  int k   = i & 255;
  wit[i] = __float2bfloat16(wi[k * NH4 + col]);
}

// Wh [256][1024] f32 -> packed MFMA B-fragments
__global__ __launch_bounds__(256) void k_cvt_whp(const float* __restrict__ wh,
                                                 bf16* __restrict__ whp) {
  int idx  = blockIdx.x * blockDim.x + threadIdx.x;
  int i    = idx & 7;
  int lane = (idx >> 3) & 63;
  int kg   = (idx >> 9) & 7;
  int nt   = idx >> 12;
  int k = kg * 32 + (lane >> 4) * 8 + i;
  int n = nt * 16 + (lane & 15);
  whp[idx] = __float2bfloat16(wh[k * NH4 + n]);
}

// poison h slots 1..tn (each chunk, before k_lstm) -> replay-deterministic
__global__ __launch_bounds__(256) void k_poison(unsigned* __restrict__ hb, int ndw) {
  int i = blockIdx.x * blockDim.x + threadIdx.x;
  if (i < ndw) hb[8192 + i] = POIS;   // slot 0 skipped (comes from hst)
}

// ---------------- zx = embed[tokens] @ Wi, written PERMUTED ----------------
// zxp byte addr for (b, lt, col): lt*131072 + g*8192 + w*2048 + rq*512 + i*128
//   + u*8 + q*2   where col=q*256+g*16+u, b=w*16+rq*4+i.
__global__ __launch_bounds__(256) void k_gemm_zx(const int*  __restrict__ tokens,
                                                 const bf16* __restrict__ eb,
                                                 const bf16* __restrict__ wit,
                                                 char* __restrict__ zxp,
                                                 int t0, int lgch) {
  __shared__ bf16 As[4 * 64 * 8];
  __shared__ bf16 Bs[4 * 64 * 8];
  int bid  = blockIdx.x;
  int nb   = bid & 15;
  int mb   = bid >> 4;
  int m0   = mb * 64, n0 = nb * 64;
  int tid  = threadIdx.x, lane = tid & 63, wave = tid >> 6;
  int wm   = wave >> 1, wn = wave & 1;
  int srow = tid >> 2;
  int skg  = tid & 3;

  int r    = m0 + srow;
  int bidx = r >> lgch;
  int lt   = r & ((1 << lgch) - 1);
  long trow = (long)tokens[bidx * NT + t0 + lt] * ND;
  const bf16* ap = eb  + trow + skg * 8;
  const bf16* bp = wit + (long)(n0 + srow) * ND + skg * 8;
  bf16* as_dst = &As[(skg * 64 + srow) * 8];
  bf16* bs_dst = &Bs[(skg * 64 + srow) * 8];

  f32x4 acc[2][2] = {};
  for (int k0 = 0; k0 < ND; k0 += 32) {
    __syncthreads();
    *(u32x4*)as_dst = *(const u32x4*)(ap + k0);
    *(u32x4*)bs_dst = *(const u32x4*)(bp + k0);
    __syncthreads();
    short8 a0 = *(const short8*)&As[((lane >> 4) * 64 + wm * 32 +  0 + (lane & 15)) * 8];
    short8 a1 = *(const short8*)&As[((lane >> 4) * 64 + wm * 32 + 16 + (lane & 15)) * 8];
    short8 b0 = *(const short8*)&Bs[((lane >> 4) * 64 + wn * 32 +  0 + (lane & 15)) * 8];
    short8 b1 = *(const short8*)&Bs[((lane >> 4) * 64 + wn * 32 + 16 + (lane & 15)) * 8];
    acc[0][0] = __builtin_amdgcn_mfma_f32_16x16x32_bf16(a0, b0, acc[0][0], 0, 0, 0);
    acc[0][1] = __builtin_amdgcn_mfma_f32_16x16x32_bf16(a0, b1, acc[0][1], 0, 0, 0);
    acc[1][0] = __builtin_amdgcn_mfma_f32_16x16x32_bf16(a1, b0, acc[1][0], 0, 0, 0);
    acc[1][1] = __builtin_amdgcn_mfma_f32_16x16x32_bf16(a1, b1, acc[1][1], 0, 0, 0);
  }
  int r_base = m0 + wm * 32 + (lane >> 4) * 4;
  int c_base = n0 + wn * 32 + (lane & 15);
  int mask = (1 << lgch) - 1;
#pragma unroll
  for (int fm = 0; fm < 2; ++fm)
#pragma unroll
    for (int fn = 0; fn < 2; ++fn)
#pragma unroll
      for (int i2 = 0; i2 < 4; ++i2) {
        int rr  = r_base + fm * 16 + i2;
        int col = c_base + fn * 16;
        int b   = rr >> lgch, lt2 = rr & mask;
        int q   = col >> 8, gg = (col >> 4) & 15, uu = col & 15;
        int w_  = b >> 4, rq_ = (b >> 2) & 3, ii = b & 3;
        size_t off = (size_t)lt2 * 131072 + gg * 8192 + w_ * 2048 + rq_ * 512 +
                     ii * 128 + uu * 8 + q * 2;
        *(bf16*)(zxp + off) = __float2bfloat16(acc[fm][fn][i2]);
      }
}

// ---------------- LSTM scan, pairwise exchange (same-XCD pairing) ----------------
// Grid = 16 blocks; ACTIVE blocks: p = bid&7 in [0,4), s = bid>>3. Partner pair
// (p, p+8) maps to the same XCD under round-robin bid%8 -> XCD (speed-only
// heuristic). WG (p,s) owns batches [16p,16p+16) x units [128s,128s+128).
// Own h-half via LDS parity buffer; partner h-half via global slot in
// MFMA-A-fragment-major layout, relaxed agent atomics vs bf16-inf poison.
// RULE-20: every register array below is indexed ONLY by compile-time
// constants; lane/blockIdx-derived values appear only in addresses.
__device__ __forceinline__ float sigf(float x) {
  return __builtin_amdgcn_rcpf(1.f + __expf(-x));
}
__device__ __forceinline__ float tanh_fast(float x) {
  return 1.f - 2.f * __builtin_amdgcn_rcpf(1.f + __expf(2.f * x));
}
__device__ __forceinline__ unsigned short f2b(float x) {
  bf16 t = __float2bfloat16(x);
  return *reinterpret_cast<unsigned short*>(&t);
}

union Frag { unsigned long long q[2]; short8 s; };

__global__ __launch_bounds__(512, 2) void k_lstm(const char* __restrict__ zxp,
                                                 const bf16* __restrict__ whp,
                                                 const float* __restrict__ bh,
                                                 float* __restrict__ cst,
                                                 float* __restrict__ hst,
                                                 unsigned* __restrict__ hbuf,
                                                 int t0, int tn) {
  __shared__ unsigned hs[2][1024];   // [parity][own-half 4KB in fragment layout]

  int bid = blockIdx.x;
  int p   = bid & 7;           // batch tile
  int s   = bid >> 3;          // unit half
  if (p >= 4) return;          // 8 spacer blocks (XCD alignment only)
  int tid = threadIdx.x;
  int l   = tid & 63;
  int wv  = tid >> 6;          // wave 0..7
  int G   = s * 8 + wv;        // unit group 0..15
  int l15 = l & 15, l4 = l >> 4;
  int u   = G * 16 + l15;      // this lane's unit

  // register-resident Wh B-fragments, split own/partner k-halves.
  short8 bw_own[4][4], bw_par[4][4];
#pragma unroll
  for (int q = 0; q < 4; ++q) {
    int nt = q * 16 + G;
#pragma unroll
    for (int r = 0; r < 4; ++r) {
      bw_own[q][r] = *(const short8*)&whp[((long)(nt * 8 + (4 * s + r)) * 64 + l) * 8];
      bw_par[q][r] = *(const short8*)&whp[((long)(nt * 8 + (4 * (1 - s) + r)) * 64 + l) * 8];
    }
  }
  float bhv[4];
#pragma unroll
  for (int q = 0; q < 4; ++q) bhv[q] = bh[q * 256 + u];

  float c[4];
#pragma unroll
  for (int i = 0; i < 4; ++i)
    c[i] = (t0 == 0) ? 0.f : cst[(p * 16 + l4 * 4 + i) * 256 + u];

  // initial A-fragments of h(t0), both halves: zeros or hst
  short8 a_own[4], a_par[4];
  if (t0 == 0) {
#pragma unroll
    for (int r = 0; r < 4; ++r) { a_own[r] = (short8)(short)0; a_par[r] = (short8)(short)0; }
  } else {
    int rowb = p * 16 + l15;
#pragma unroll
    for (int r = 0; r < 4; ++r) {
      {
        const float* hp = &hst[rowb * 256 + l4 * 8 + (4 * s + r) * 32];
        float4 f0 = *(const float4*)hp;
        float4 f1 = *(const float4*)(hp + 4);
        unsigned short e[8] = {f2b(f0.x), f2b(f0.y), f2b(f0.z), f2b(f0.w),
                               f2b(f1.x), f2b(f1.y), f2b(f1.z), f2b(f1.w)};
        a_own[r] = *(const short8*)e;
      }
      {
        const float* hp = &hst[rowb * 256 + l4 * 8 + (4 * (1 - s) + r) * 32];
        float4 f0 = *(const float4*)hp;
        float4 f1 = *(const float4*)(hp + 4);
        unsigned short e[8] = {f2b(f0.x), f2b(f0.y), f2b(f0.z), f2b(f0.w),
                               f2b(f1.x), f2b(f1.y), f2b(f1.z), f2b(f1.w)};
        a_par[r] = *(const short8*)e;
      }
    }
  }

  const char* zbase = zxp + G * 8192 + p * 2048 + l4 * 512 + l15 * 8;
  unsigned long long* hb64 = (unsigned long long*)hbuf;

  // zx prefetch for step 0
  uint2 z0[4], z1[4];
#pragma unroll
  for (int i = 0; i < 4; ++i) z0[i] = *(const uint2*)(zbase + i * 128);

  // producer constants
  int hi   = (2 * G + (l15 >> 3)) & 3;    // dest-lane hi bits of this lane's unit
  int rown = (G >> 1) & 3;                // own-half region for publishing
  int jw   = (l15 & 7) >> 1;              // dword-within-16B
  bool even = ((l & 1) == 0);

  for (int lt = 0; lt < tn; ++lt) {
    // prefetch next step's zx (independent of h)
    if (lt + 1 < tn) {
#pragma unroll
      for (int i = 0; i < 4; ++i)
        z1[i] = *(const uint2*)(zbase + (size_t)(lt + 1) * 131072 + i * 128);
    }

    // own half A-fragments from LDS (written last iter, parity lt&1)
    if (lt > 0) {
      const unsigned* hp = hs[lt & 1];
#pragma unroll
      for (int r = 0; r < 4; ++r)
        a_own[r] = *(const short8*)&hp[(r * 64 + l) * 4];
    }

    // own-half MFMAs first (hides partner store->visibility latency)
    f32x4 acc[4] = {};
#pragma unroll
    for (int r = 0; r < 4; ++r) {
#pragma unroll
      for (int q = 0; q < 4; ++q)
        acc[q] = __builtin_amdgcn_mfma_f32_16x16x32_bf16(a_own[r], bw_own[q][r],
                                                         acc[q], 0, 0, 0);
    }

    // partner half: poll its 4KB fragment region (coalesced), bounded spin
    if (lt > 0) {
      unsigned long long* sb = hb64 + (size_t)lt * 4096 + p * 1024 + (1 - s) * 512;
      Frag fr[4];
      for (unsigned spin = 0; spin < 65536u; ++spin) {
#pragma unroll
        for (int r = 0; r < 4; ++r) {
          fr[r].q[0] = __hip_atomic_load(sb + (r * 64 + l) * 2,
                                         __ATOMIC_RELAXED, __HIP_MEMORY_SCOPE_AGENT);
          fr[r].q[1] = __hip_atomic_load(sb + (r * 64 + l) * 2 + 1,
                                         __ATOMIC_RELAXED, __HIP_MEMORY_SCOPE_AGENT);
        }
        bool bad = false;
#pragma unroll
        for (int r = 0; r < 4; ++r) {
          unsigned long long q0 = fr[r].q[0], q1 = fr[r].q[1];
          bad |= ((unsigned)q0 == POIS) | ((unsigned)(q0 >> 32) == POIS) |
                 ((unsigned)q1 == POIS) | ((unsigned)(q1 >> 32) == POIS);
        }
        if (!__any(bad)) break;
      }
#pragma unroll
      for (int r = 0; r < 4; ++r) a_par[r] = fr[r].s;
    }

#pragma unroll
    for (int r = 0; r < 4; ++r) {
#pragma unroll
      for (int q = 0; q < 4; ++q)
        acc[q] = __builtin_amdgcn_mfma_f32_16x16x32_bf16(a_par[r], bw_par[q][r],
                                                         acc[q], 0, 0, 0);
    }

    // gates: lane owns (4 batches x unit u)
    unsigned my0, my1, my2, my3;
    float hv[4];
    {
      float zi, zf, zg, zo;
      zi = acc[0][0] + __uint_as_float((z0[0].x & 0xFFFFu) << 16) + bhv[0];
      zf = acc[1][0] + __uint_as_float((z0[0].x >> 16) << 16)     + bhv[1];
      zg = acc[2][0] + __uint_as_float((z0[0].y & 0xFFFFu) << 16) + bhv[2];
      zo = acc[3][0] + __uint_as_float((z0[0].y >> 16) << 16)     + bhv[3];
      c[0] = sigf(zf) * c[0] + sigf(zi) * tanh_fast(zg);
      hv[0] = sigf(zo) * tanh_fast(c[0]);  my0 = f2b(hv[0]);
      zi = acc[0][1] + __uint_as_float((z0[1].x & 0xFFFFu) << 16) + bhv[0];
      zf = acc[1][1] + __uint_as_float((z0[1].x >> 16) << 16)     + bhv[1];
      zg = acc[2][1] + __uint_as_float((z0[1].y & 0xFFFFu) << 16) + bhv[2];
      zo = acc[3][1] + __uint_as_float((z0[1].y >> 16) << 16)     + bhv[3];
      c[1] = sigf(zf) * c[1] + sigf(zi) * tanh_fast(zg);
      hv[1] = sigf(zo) * tanh_fast(c[1]);  my1 = f2b(hv[1]);
      zi = acc[0][2] + __uint_as_float((z0[2].x & 0xFFFFu) << 16) + bhv[0];
      zf = acc[1][2] + __uint_as_float((z0[2].x >> 16) << 16)     + bhv[1];
      zg = acc[2][2] + __uint_as_float((z0[2].y & 0xFFFFu) << 16) + bhv[2];
      zo = acc[3][2] + __uint_as_float((z0[2].y >> 16) << 16)     + bhv[3];
      c[2] = sigf(zf) * c[2] + sigf(zi) * tanh_fast(zg);
      hv[2] = sigf(zo) * tanh_fast(c[2]);  my2 = f2b(hv[2]);
      zi = acc[0][3] + __uint_as_float((z0[3].x & 0xFFFFu) << 16) + bhv[0];
      zf = acc[1][3] + __uint_as_float((z0[3].x >> 16) << 16)     + bhv[1];
      zg = acc[2][3] + __uint_as_float((z0[3].y & 0xFFFFu) << 16) + bhv[2];
      zo = acc[3][3] + __uint_as_float((z0[3].y >> 16) << 16)     + bhv[3];
      c[3] = sigf(zf) * c[3] + sigf(zi) * tanh_fast(zg);
      hv[3] = sigf(zo) * tanh_fast(c[3]);  my3 = f2b(hv[3]);
    }

    // publish: STATIC-INDEX packing (rule-20 fix). Even lane writes batches
    // {0,1} of its unit pair, odd lane batches {2,3}; runtime parity only in
    // the selects and addresses, never as an array index.
    unsigned pt0 = (unsigned)__shfl_xor((int)my0, 1, 64);
    unsigned pt1 = (unsigned)__shfl_xor((int)my1, 1, 64);
    unsigned pt2 = (unsigned)__shfl_xor((int)my2, 1, 64);
    unsigned pt3 = (unsigned)__shfl_xor((int)my3, 1, 64);
    unsigned dwA = even ? (my0 | (pt0 << 16)) : (pt2 | (my2 << 16));
    unsigned dwB = even ? (my1 | (pt1 << 16)) : (pt3 | (my3 << 16));
    int ia = even ? 0 : 2;
    unsigned* gdst = hbuf + (size_t)(lt + 1) * 8192 + p * 2048 + s * 1024;
    unsigned* ldst = hs[(lt + 1) & 1];
    int idxA = (rown * 64 + ((l4 * 4 + ia) | (hi << 4))) * 4 + jw;
    int idxB = (rown * 64 + ((l4 * 4 + ia + 1) | (hi << 4))) * 4 + jw;
    __hip_atomic_store(gdst + idxA, dwA, __ATOMIC_RELAXED, __HIP_MEMORY_SCOPE_AGENT);
    __hip_atomic_store(gdst + idxB, dwB, __ATOMIC_RELAXED, __HIP_MEMORY_SCOPE_AGENT);
    ldst[idxA] = dwA;
    ldst[idxB] = dwB;

    if (lt == tn - 1) {
#pragma unroll
      for (int i = 0; i < 4; ++i)
        hst[(p * 16 + l4 * 4 + i) * 256 + u] = hv[i];
    }

    __syncthreads();
#pragma unroll
    for (int i = 0; i < 4; ++i) z0[i] = z1[i];
  }

#pragma unroll
  for (int i = 0; i < 4; ++i)
    cst[(p * 16 + l4 * 4 + i) * 256 + u] = c[i];
}

// ---------------- y = h @ Wo + bo ----------------
__global__ __launch_bounds__(64) void k_out(const float* __restrict__ hfin,
                                            const float* __restrict__ wo,
                                            const float* __restrict__ bo,
                                            float* __restrict__ y) {
  __shared__ float hsm[256];
  int b = blockIdx.x, tid = threadIdx.x;
  for (int i = tid; i < 256; i += 64) hsm[i] = hfin[b * 256 + i];
  __syncthreads();
  if (tid < NCLS) {
    float s = bo[tid];
    for (int k = 0; k < 256; ++k) s += hsm[k] * wo[k * NCLS + tid];
    y[b * NCLS + tid] = s;
  }
}

// ---------------- launcher ----------------
extern "C" void kernel_launch(void* const* d_in, const int* in_sizes, int n_in,
                              void* d_out, int out_size, void* d_ws, size_t ws_size,
                              hipStream_t stream) {
  const int*   tokens = (const int*)d_in[0];
  const float* embed  = (const float*)d_in[3];
  const float* wi     = (const float*)d_in[4];
  const float* wh     = (const float*)d_in[5];
  const float* bh     = (const float*)d_in[6];
  const float* wo     = (const float*)d_in[7];
  const float* bo     = (const float*)d_in[8];
  float* y = (float*)d_out;

  char* ws = (char*)d_ws;
  bf16* eb     = (bf16*)ws;     ws += (size_t)NV * ND * 2;        // 16.38 MB
  bf16* wit    = (bf16*)ws;     ws += (size_t)NH4 * ND * 2;       // 0.5 MB
  bf16* whp    = (bf16*)ws;     ws += (size_t)ND * NH4 * 2;       // 0.5 MB
  float* cst   = (float*)ws;    ws += (size_t)NB * ND * 4;        // 64 KB
  float* hst   = (float*)ws;    ws += (size_t)NB * ND * 4;        // 64 KB
  size_t fixed = (size_t)(ws - (char*)d_ws);

  // pick largest chunk: need = fixed + hbuf((ch+1)*32KB) + zxp(ch*128KB)
  int CHUNK = 32, lgch = 5;
  static const int cand[]  = {2048, 1024, 512, 256, 128, 64, 32};
  static const int candl[] = {11, 10, 9, 8, 7, 6, 5};
  for (int ci = 0; ci < 7; ++ci) {
    size_t need = fixed + (size_t)(cand[ci] + 1) * 32768 + (size_t)cand[ci] * 131072;
    if (need <= ws_size) { CHUNK = cand[ci]; lgch = candl[ci]; break; }
  }
  unsigned* hbuf = (unsigned*)ws;  ws += (size_t)(CHUNK + 1) * 32768;
  char* zxp = ws;

  hipLaunchKernelGGL(k_cvt_embed, dim3(NV * ND / 4 / 256), dim3(256), 0, stream, embed, eb);
  hipLaunchKernelGGL(k_cvt_wi,    dim3(NH4 * ND / 256), dim3(256), 0, stream, wi, wit);
  hipLaunchKernelGGL(k_cvt_whp,   dim3(ND * NH4 / 256), dim3(256), 0, stream, wh, whp);

  for (int t0 = 0; t0 < NT; t0 += CHUNK) {
    hipLaunchKernelGGL(k_gemm_zx, dim3(CHUNK * 16), dim3(256), 0, stream,
                       tokens, eb, wit, zxp, t0, lgch);
    hipLaunchKernelGGL(k_poison, dim3(CHUNK * 32), dim3(256), 0, stream,
                       hbuf, CHUNK * 8192);
    hipLaunchKernelGGL(k_lstm, dim3(16), dim3(512), 0, stream,
                       zxp, whp, bh, cst, hst, hbuf, t0, CHUNK);
  }
  hipLaunchKernelGGL(k_out, dim3(NB), dim3(64), 0, stream, hst, wo, bo, y);
}

// Round 9
// 4019.406 us; speedup vs baseline: 72.3140x; 1.0111x over previous
//
#include <hip/hip_runtime.h>
#include <hip/hip_bf16.h>
#include <stdint.h>

typedef __hip_bfloat16 bf16;
typedef __attribute__((ext_vector_type(8))) short short8;
typedef __attribute__((ext_vector_type(4))) float f32x4;
typedef __attribute__((ext_vector_type(4))) unsigned int u32x4;

#define NB   64
#define NT   2048
#define NV   32000
#define ND   256
#define NH4  1024
#define NCLS 27
#define POIS 0x7F807F80u

// ---------------- dtype conversion / packing ----------------

__global__ __launch_bounds__(256) void k_cvt_embed(const float* __restrict__ e,
                                                   bf16* __restrict__ o) {
  int i = blockIdx.x * blockDim.x + threadIdx.x;
  float4 v = reinterpret_cast<const float4*>(e)[i];
  union { bf16 h[4]; uint2 u; } pk;
  pk.h[0] = __float2bfloat16(v.x);
  pk.h[1] = __float2bfloat16(v.y);
  pk.h[2] = __float2bfloat16(v.z);
  pk.h[3] = __float2bfloat16(v.w);
  reinterpret_cast<uint2*>(o)[i] = pk.u;
}

// Wi [256][1024] f32 -> Wi_t [1024][256] bf16
__global__ __launch_bounds__(256) void k_cvt_wi(const float* __restrict__ wi,
                                                bf16* __restrict__ wit) {
  int i = blockIdx.x * blockDim.x + threadIdx.x;
  int col = i >> 8;
  int k   = i & 255;
  wit[i] = __float2bfloat16(wi[k * NH4 + col]);
}

// Wh [256][1024] f32 -> packed MFMA B-fragments
__global__ __launch_bounds__(256) void k_cvt_whp(const float* __restrict__ wh,
                                                 bf16* __restrict__ whp) {
  int idx  = blockIdx.x * blockDim.x + threadIdx.x;
  int i    = idx & 7;
  int lane = (idx >> 3) & 63;
  int kg   = (idx >> 9) & 7;
  int nt   = idx >> 12;
  int k = kg * 32 + (lane >> 4) * 8 + i;
  int n = nt * 16 + (lane & 15);
  whp[idx] = __float2bfloat16(wh[k * NH4 + n]);
}

// poison h slots 1..tn (each chunk, before k_lstm) -> replay-deterministic
__global__ __launch_bounds__(256) void k_poison(unsigned* __restrict__ hb, int ndw) {
  int i = blockIdx.x * blockDim.x + threadIdx.x;
  if (i < ndw) hb[8192 + i] = POIS;   // slot 0 skipped (comes from hst)
}

// ---------------- zx = embed[tokens] @ Wi, written PERMUTED ----------------
// zxp byte addr for (b, lt, col): lt*131072 + g*8192 + w*2048 + rq*512 + i*128
//   + u*8 + q*2   where col=q*256+g*16+u, b=w*16+rq*4+i.
__global__ __launch_bounds__(256) void k_gemm_zx(const int*  __restrict__ tokens,
                                                 const bf16* __restrict__ eb,
                                                 const bf16* __restrict__ wit,
                                                 char* __restrict__ zxp,
                                                 int t0, int lgch) {
  __shared__ bf16 As[4 * 64 * 8];
  __shared__ bf16 Bs[4 * 64 * 8];
  int bid  = blockIdx.x;
  int nb   = bid & 15;
  int mb   = bid >> 4;
  int m0   = mb * 64, n0 = nb * 64;
  int tid  = threadIdx.x, lane = tid & 63, wave = tid >> 6;
  int wm   = wave >> 1, wn = wave & 1;
  int srow = tid >> 2;
  int skg  = tid & 3;

  int r    = m0 + srow;
  int bidx = r >> lgch;
  int lt   = r & ((1 << lgch) - 1);
  long trow = (long)tokens[bidx * NT + t0 + lt] * ND;
  const bf16* ap = eb  + trow + skg * 8;
  const bf16* bp = wit + (long)(n0 + srow) * ND + skg * 8;
  bf16* as_dst = &As[(skg * 64 + srow) * 8];
  bf16* bs_dst = &Bs[(skg * 64 + srow) * 8];

  f32x4 acc[2][2] = {};
  for (int k0 = 0; k0 < ND; k0 += 32) {
    __syncthreads();
    *(u32x4*)as_dst = *(const u32x4*)(ap + k0);
    *(u32x4*)bs_dst = *(const u32x4*)(bp + k0);
    __syncthreads();
    short8 a0 = *(const short8*)&As[((lane >> 4) * 64 + wm * 32 +  0 + (lane & 15)) * 8];
    short8 a1 = *(const short8*)&As[((lane >> 4) * 64 + wm * 32 + 16 + (lane & 15)) * 8];
    short8 b0 = *(const short8*)&Bs[((lane >> 4) * 64 + wn * 32 +  0 + (lane & 15)) * 8];
    short8 b1 = *(const short8*)&Bs[((lane >> 4) * 64 + wn * 32 + 16 + (lane & 15)) * 8];
    acc[0][0] = __builtin_amdgcn_mfma_f32_16x16x32_bf16(a0, b0, acc[0][0], 0, 0, 0);
    acc[0][1] = __builtin_amdgcn_mfma_f32_16x16x32_bf16(a0, b1, acc[0][1], 0, 0, 0);
    acc[1][0] = __builtin_amdgcn_mfma_f32_16x16x32_bf16(a1, b0, acc[1][0], 0, 0, 0);
    acc[1][1] = __builtin_amdgcn_mfma_f32_16x16x32_bf16(a1, b1, acc[1][1], 0, 0, 0);
  }
  int r_base = m0 + wm * 32 + (lane >> 4) * 4;
  int c_base = n0 + wn * 32 + (lane & 15);
  int mask = (1 << lgch) - 1;
#pragma unroll
  for (int fm = 0; fm < 2; ++fm)
#pragma unroll
    for (int fn = 0; fn < 2; ++fn)
#pragma unroll
      for (int i2 = 0; i2 < 4; ++i2) {
        int rr  = r_base + fm * 16 + i2;
        int col = c_base + fn * 16;
        int b   = rr >> lgch, lt2 = rr & mask;
        int q   = col >> 8, gg = (col >> 4) & 15, uu = col & 15;
        int w_  = b >> 4, rq_ = (b >> 2) & 3, ii = b & 3;
        size_t off = (size_t)lt2 * 131072 + gg * 8192 + w_ * 2048 + rq_ * 512 +
                     ii * 128 + uu * 8 + q * 2;
        *(bf16*)(zxp + off) = __float2bfloat16(acc[fm][fn][i2]);
      }
}

// ---------------- LSTM scan, pairwise exchange (same-XCD pairing) ----------------
// Grid = 16 blocks; ACTIVE blocks: p = bid&7 in [0,4), s = bid>>3. Partner pair
// (p, p+8) -> same XCD under round-robin bid%8 -> XCD (speed heuristic only).
// WG (p,s) owns batches [16p,16p+16) x units [128s,128s+128). Own h-half via
// LDS parity buffer; partner h-half via global slot in MFMA-A-fragment-major
// layout, relaxed agent atomics vs bf16-inf poison.
// R9 FIX: __launch_bounds__(512,1) (R8's (512,2) capped VGPR at 128 -> weights
// streamed from L2 every step + scratch spills = 49MB/dispatch WRITE) and
// asm-pinned weight fragments (un-rematerializable -> must stay in VGPRs).
__device__ __forceinline__ float sigf(float x) {
  return __builtin_amdgcn_rcpf(1.f + __expf(-x));
}
__device__ __forceinline__ float tanh_fast(float x) {
  return 1.f - 2.f * __builtin_amdgcn_rcpf(1.f + __expf(2.f * x));
}
__device__ __forceinline__ unsigned short f2b(float x) {
  bf16 t = __float2bfloat16(x);
  return *reinterpret_cast<unsigned short*>(&t);
}

union Frag { unsigned long long q[2]; short8 s; };

__global__ __launch_bounds__(512, 1) void k_lstm(const char* __restrict__ zxp,
                                                 const bf16* __restrict__ whp,
                                                 const float* __restrict__ bh,
                                                 float* __restrict__ cst,
                                                 float* __restrict__ hst,
                                                 unsigned* __restrict__ hbuf,
                                                 int t0, int tn) {
  __shared__ unsigned hs[2][1024];   // [parity][own-half 4KB in fragment layout]

  int bid = blockIdx.x;
  int p   = bid & 7;           // batch tile
  int s   = bid >> 3;          // unit half
  if (p >= 4) return;          // 8 spacer blocks (XCD alignment only)
  int tid = threadIdx.x;
  int l   = tid & 63;
  int wv  = tid >> 6;          // wave 0..7
  int G   = s * 8 + wv;        // unit group 0..15
  int l15 = l & 15, l4 = l >> 4;
  int u   = G * 16 + l15;      // this lane's unit

  // register-resident Wh B-fragments, split own/partner k-halves.
  short8 bw_own[4][4], bw_par[4][4];
#pragma unroll
  for (int q = 0; q < 4; ++q) {
    int nt = q * 16 + G;
#pragma unroll
    for (int r = 0; r < 4; ++r) {
      bw_own[q][r] = *(const short8*)&whp[((long)(nt * 8 + (4 * s + r)) * 64 + l) * 8];
      bw_par[q][r] = *(const short8*)&whp[((long)(nt * 8 + (4 * (1 - s) + r)) * 64 + l) * 8];
    }
  }
  // PIN: make each fragment's origin opaque so the compiler cannot sink the
  // whp loads into the loop (L2 re-stream) nor spill-rematerialize them.
#pragma unroll
  for (int q = 0; q < 4; ++q)
#pragma unroll
    for (int r = 0; r < 4; ++r) {
      asm volatile("" : "+v"(bw_own[q][r]));
      asm volatile("" : "+v"(bw_par[q][r]));
    }

  float bhv[4];
#pragma unroll
  for (int q = 0; q < 4; ++q) bhv[q] = bh[q * 256 + u];

  float c[4];
#pragma unroll
  for (int i = 0; i < 4; ++i)
    c[i] = (t0 == 0) ? 0.f : cst[(p * 16 + l4 * 4 + i) * 256 + u];

  // initial A-fragments of h(t0), both halves: zeros or hst
  short8 a_own[4], a_par[4];
  if (t0 == 0) {
#pragma unroll
    for (int r = 0; r < 4; ++r) { a_own[r] = (short8)(short)0; a_par[r] = (short8)(short)0; }
  } else {
    int rowb = p * 16 + l15;
#pragma unroll
    for (int r = 0; r < 4; ++r) {
      {
        const float* hp = &hst[rowb * 256 + l4 * 8 + (4 * s + r) * 32];
        float4 f0 = *(const float4*)hp;
        float4 f1 = *(const float4*)(hp + 4);
        unsigned short e[8] = {f2b(f0.x), f2b(f0.y), f2b(f0.z), f2b(f0.w),
                               f2b(f1.x), f2b(f1.y), f2b(f1.z), f2b(f1.w)};
        a_own[r] = *(const short8*)e;
      }
      {
        const float* hp = &hst[rowb * 256 + l4 * 8 + (4 * (1 - s) + r) * 32];
        float4 f0 = *(const float4*)hp;
        float4 f1 = *(const float4*)(hp + 4);
        unsigned short e[8] = {f2b(f0.x), f2b(f0.y), f2b(f0.z), f2b(f0.w),
                               f2b(f1.x), f2b(f1.y), f2b(f1.z), f2b(f1.w)};
        a_par[r] = *(const short8*)e;
      }
    }
  }

  const char* zbase = zxp + G * 8192 + p * 2048 + l4 * 512 + l15 * 8;
  unsigned long long* hb64 = (unsigned long long*)hbuf;

  // zx prefetch for step 0
  uint2 z0[4], z1[4];
#pragma unroll
  for (int i = 0; i < 4; ++i) z0[i] = *(const uint2*)(zbase + i * 128);

  // producer constants
  int hi   = (2 * G + (l15 >> 3)) & 3;    // dest-lane hi bits of this lane's unit
  int rown = (G >> 1) & 3;                // own-half region for publishing
  int jw   = (l15 & 7) >> 1;              // dword-within-16B
  bool even = ((l & 1) == 0);

  for (int lt = 0; lt < tn; ++lt) {
    // prefetch next step's zx (independent of h)
    if (lt + 1 < tn) {
#pragma unroll
      for (int i = 0; i < 4; ++i)
        z1[i] = *(const uint2*)(zbase + (size_t)(lt + 1) * 131072 + i * 128);
    }

    // own half A-fragments from LDS (written last iter, parity lt&1)
    if (lt > 0) {
      const unsigned* hp = hs[lt & 1];
#pragma unroll
      for (int r = 0; r < 4; ++r)
        a_own[r] = *(const short8*)&hp[(r * 64 + l) * 4];
    }

    // own-half MFMAs first (hides partner store->visibility latency)
    f32x4 acc[4] = {};
#pragma unroll
    for (int r = 0; r < 4; ++r) {
#pragma unroll
      for (int q = 0; q < 4; ++q)
        acc[q] = __builtin_amdgcn_mfma_f32_16x16x32_bf16(a_own[r], bw_own[q][r],
                                                         acc[q], 0, 0, 0);
    }

    // partner half: poll its 4KB fragment region (coalesced), bounded spin
    if (lt > 0) {
      unsigned long long* sb = hb64 + (size_t)lt * 4096 + p * 1024 + (1 - s) * 512;
      Frag fr[4];
      for (unsigned spin = 0; spin < 65536u; ++spin) {
#pragma unroll
        for (int r = 0; r < 4; ++r) {
          fr[r].q[0] = __hip_atomic_load(sb + (r * 64 + l) * 2,
                                         __ATOMIC_RELAXED, __HIP_MEMORY_SCOPE_AGENT);
          fr[r].q[1] = __hip_atomic_load(sb + (r * 64 + l) * 2 + 1,
                                         __ATOMIC_RELAXED, __HIP_MEMORY_SCOPE_AGENT);
        }
        bool bad = false;
#pragma unroll
        for (int r = 0; r < 4; ++r) {
          unsigned long long q0 = fr[r].q[0], q1 = fr[r].q[1];
          bad |= ((unsigned)q0 == POIS) | ((unsigned)(q0 >> 32) == POIS) |
                 ((unsigned)q1 == POIS) | ((unsigned)(q1 >> 32) == POIS);
        }
        if (!__any(bad)) break;
      }
#pragma unroll
      for (int r = 0; r < 4; ++r) a_par[r] = fr[r].s;
    }

#pragma unroll
    for (int r = 0; r < 4; ++r) {
#pragma unroll
      for (int q = 0; q < 4; ++q)
        acc[q] = __builtin_amdgcn_mfma_f32_16x16x32_bf16(a_par[r], bw_par[q][r],
                                                         acc[q], 0, 0, 0);
    }

    // gates: lane owns (4 batches x unit u)
    unsigned my0, my1, my2, my3;
    float hv[4];
    {
      float zi, zf, zg, zo;
      zi = acc[0][0] + __uint_as_float((z0[0].x & 0xFFFFu) << 16) + bhv[0];
      zf = acc[1][0] + __uint_as_float((z0[0].x >> 16) << 16)     + bhv[1];
      zg = acc[2][0] + __uint_as_float((z0[0].y & 0xFFFFu) << 16) + bhv[2];
      zo = acc[3][0] + __uint_as_float((z0[0].y >> 16) << 16)     + bhv[3];
      c[0] = sigf(zf) * c[0] + sigf(zi) * tanh_fast(zg);
      hv[0] = sigf(zo) * tanh_fast(c[0]);  my0 = f2b(hv[0]);
      zi = acc[0][1] + __uint_as_float((z0[1].x & 0xFFFFu) << 16) + bhv[0];
      zf = acc[1][1] + __uint_as_float((z0[1].x >> 16) << 16)     + bhv[1];
      zg = acc[2][1] + __uint_as_float((z0[1].y & 0xFFFFu) << 16) + bhv[2];
      zo = acc[3][1] + __uint_as_float((z0[1].y >> 16) << 16)     + bhv[3];
      c[1] = sigf(zf) * c[1] + sigf(zi) * tanh_fast(zg);
      hv[1] = sigf(zo) * tanh_fast(c[1]);  my1 = f2b(hv[1]);
      zi = acc[0][2] + __uint_as_float((z0[2].x & 0xFFFFu) << 16) + bhv[0];
      zf = acc[1][2] + __uint_as_float((z0[2].x >> 16) << 16)     + bhv[1];
      zg = acc[2][2] + __uint_as_float((z0[2].y & 0xFFFFu) << 16) + bhv[2];
      zo = acc[3][2] + __uint_as_float((z0[2].y >> 16) << 16)     + bhv[3];
      c[2] = sigf(zf) * c[2] + sigf(zi) * tanh_fast(zg);
      hv[2] = sigf(zo) * tanh_fast(c[2]);  my2 = f2b(hv[2]);
      zi = acc[0][3] + __uint_as_float((z0[3].x & 0xFFFFu) << 16) + bhv[0];
      zf = acc[1][3] + __uint_as_float((z0[3].x >> 16) << 16)     + bhv[1];
      zg = acc[2][3] + __uint_as_float((z0[3].y & 0xFFFFu) << 16) + bhv[2];
      zo = acc[3][3] + __uint_as_float((z0[3].y >> 16) << 16)     + bhv[3];
      c[3] = sigf(zf) * c[3] + sigf(zi) * tanh_fast(zg);
      hv[3] = sigf(zo) * tanh_fast(c[3]);  my3 = f2b(hv[3]);
    }

    // publish: static-index packing; runtime parity only in selects/addresses.
    unsigned pt0 = (unsigned)__shfl_xor((int)my0, 1, 64);
    unsigned pt1 = (unsigned)__shfl_xor((int)my1, 1, 64);
    unsigned pt2 = (unsigned)__shfl_xor((int)my2, 1, 64);
    unsigned pt3 = (unsigned)__shfl_xor((int)my3, 1, 64);
    unsigned dwA = even ? (my0 | (pt0 << 16)) : (pt2 | (my2 << 16));
    unsigned dwB = even ? (my1 | (pt1 << 16)) : (pt3 | (my3 << 16));
    int ia = even ? 0 : 2;
    unsigned* gdst = hbuf + (size_t)(lt + 1) * 8192 + p * 2048 + s * 1024;
    unsigned* ldst = hs[(lt + 1) & 1];
    int idxA = (rown * 64 + ((l4 * 4 + ia) | (hi << 4))) * 4 + jw;
    int idxB = (rown * 64 + ((l4 * 4 + ia + 1) | (hi << 4))) * 4 + jw;
    __hip_atomic_store(gdst + idxA, dwA, __ATOMIC_RELAXED, __HIP_MEMORY_SCOPE_AGENT);
    __hip_atomic_store(gdst + idxB, dwB, __ATOMIC_RELAXED, __HIP_MEMORY_SCOPE_AGENT);
    ldst[idxA] = dwA;
    ldst[idxB] = dwB;

    if (lt == tn - 1) {
#pragma unroll
      for (int i = 0; i < 4; ++i)
        hst[(p * 16 + l4 * 4 + i) * 256 + u] = hv[i];
    }

    __syncthreads();
#pragma unroll
    for (int i = 0; i < 4; ++i) z0[i] = z1[i];
  }

#pragma unroll
  for (int i = 0; i < 4; ++i)
    cst[(p * 16 + l4 * 4 + i) * 256 + u] = c[i];
}

// ---------------- y = h @ Wo + bo ----------------
__global__ __launch_bounds__(64) void k_out(const float* __restrict__ hfin,
                                            const float* __restrict__ wo,
                                            const float* __restrict__ bo,
                                            float* __restrict__ y) {
  __shared__ float hsm[256];
  int b = blockIdx.x, tid = threadIdx.x;
  for (int i = tid; i < 256; i += 64) hsm[i] = hfin[b * 256 + i];
  __syncthreads();
  if (tid < NCLS) {
    float s = bo[tid];
    for (int k = 0; k < 256; ++k) s += hsm[k] * wo[k * NCLS + tid];
    y[b * NCLS + tid] = s;
  }
}

// ---------------- launcher ----------------
extern "C" void kernel_launch(void* const* d_in, const int* in_sizes, int n_in,
                              void* d_out, int out_size, void* d_ws, size_t ws_size,
                              hipStream_t stream) {
  const int*   tokens = (const int*)d_in[0];
  const float* embed  = (const float*)d_in[3];
  const float* wi     = (const float*)d_in[4];
  const float* wh     = (const float*)d_in[5];
  const float* bh     = (const float*)d_in[6];
  const float* wo     = (const float*)d_in[7];
  const float* bo     = (const float*)d_in[8];
  float* y = (float*)d_out;

  char* ws = (char*)d_ws;
  bf16* eb     = (bf16*)ws;     ws += (size_t)NV * ND * 2;        // 16.38 MB
  bf16* wit    = (bf16*)ws;     ws += (size_t)NH4 * ND * 2;       // 0.5 MB
  bf16* whp    = (bf16*)ws;     ws += (size_t)ND * NH4 * 2;       // 0.5 MB
  float* cst   = (float*)ws;    ws += (size_t)NB * ND * 4;        // 64 KB
  float* hst   = (float*)ws;    ws += (size_t)NB * ND * 4;        // 64 KB
  size_t fixed = (size_t)(ws - (char*)d_ws);

  // pick largest chunk: need = fixed + hbuf((ch+1)*32KB) + zxp(ch*128KB)
  int CHUNK = 32, lgch = 5;
  static const int cand[]  = {2048, 1024, 512, 256, 128, 64, 32};
  static const int candl[] = {11, 10, 9, 8, 7, 6, 5};
  for (int ci = 0; ci < 7; ++ci) {
    size_t need = fixed + (size_t)(cand[ci] + 1) * 32768 + (size_t)cand[ci] * 131072;
    if (need <= ws_size) { CHUNK = cand[ci]; lgch = candl[ci]; break; }
  }
  unsigned* hbuf = (unsigned*)ws;  ws += (size_t)(CHUNK + 1) * 32768;
  char* zxp = ws;

  hipLaunchKernelGGL(k_cvt_embed, dim3(NV * ND / 4 / 256), dim3(256), 0, stream, embed, eb);
  hipLaunchKernelGGL(k_cvt_wi,    dim3(NH4 * ND / 256), dim3(256), 0, stream, wi, wit);
  hipLaunchKernelGGL(k_cvt_whp,   dim3(ND * NH4 / 256), dim3(256), 0, stream, wh, whp);

  for (int t0 = 0; t0 < NT; t0 += CHUNK) {
    hipLaunchKernelGGL(k_gemm_zx, dim3(CHUNK * 16), dim3(256), 0, stream,
                       tokens, eb, wit, zxp, t0, lgch);
    hipLaunchKernelGGL(k_poison, dim3(CHUNK * 32), dim3(256), 0, stream,
                       hbuf, CHUNK * 8192);
    hipLaunchKernelGGL(k_lstm, dim3(16), dim3(512), 0, stream,
                       zxp, whp, bh, cst, hst, hbuf, t0, CHUNK);
  }
  hipLaunchKernelGGL(k_out, dim3(NB), dim3(64), 0, stream, hst, wo, bo, y);
}